// Round 1
// baseline (1160.823 us; speedup 1.0000x reference)
//
#include <hip/hip_runtime.h>
#include <stdint.h>

// ============================================================================
// JAX threefry2x32 PRNG reproduction.
// JAX_PARTITIONABLE=1: jax >= 0.4.36 default (split = fold_in(key, i),
//   random_bits = o0^o1 of threefry(key; hi(e), lo(e))).
// JAX_PARTITIONABLE=0: legacy scheme (iota split into halves).
// ============================================================================
#define JAX_PARTITIONABLE 1

struct U2 { unsigned a, b; };

__device__ __forceinline__ unsigned rotl32(unsigned v, int r) {
  return (v << r) | (v >> (32 - r));
}

__device__ __forceinline__ U2 tf(U2 k, unsigned x0, unsigned x1) {
  unsigned ks0 = k.a, ks1 = k.b, ks2 = k.a ^ k.b ^ 0x1BD11BDAu;
  x0 += ks0; x1 += ks1;
#define TFG(RA, RB, RC, RD, KA, KB, INC)                  \
  x0 += x1; x1 = rotl32(x1, RA); x1 ^= x0;                \
  x0 += x1; x1 = rotl32(x1, RB); x1 ^= x0;                \
  x0 += x1; x1 = rotl32(x1, RC); x1 ^= x0;                \
  x0 += x1; x1 = rotl32(x1, RD); x1 ^= x0;                \
  x0 += KA; x1 += KB + INC;
  TFG(13, 15, 26, 6, ks1, ks2, 1u)
  TFG(17, 29, 16, 24, ks2, ks0, 2u)
  TFG(13, 15, 26, 6, ks0, ks1, 3u)
  TFG(17, 29, 16, 24, ks1, ks2, 4u)
  TFG(13, 15, 26, 6, ks2, ks0, 5u)
#undef TFG
  U2 r; r.a = x0; r.b = x1; return r;
}

#if JAX_PARTITIONABLE
// split(key, num)[j] = threefry(key; 0, j)  (fold_in semantics)
__device__ __forceinline__ U2 split_key(U2 key, int num, int j) {
  (void)num;
  return tf(key, 0u, (unsigned)j);
}
// random_bits(key, n)[e] = o0 ^ o1 of threefry(key; e>>32, e&0xffffffff)
__device__ __forceinline__ unsigned random_bits(U2 key, int n, unsigned e) {
  (void)n;
  U2 r = tf(key, 0u, e);
  return r.a ^ r.b;
}
#else
// legacy: out[i] of split/bits over iota halves
__device__ __forceinline__ unsigned split_elem(U2 key, int num, int i) {
  if (i < num) { U2 r = tf(key, (unsigned)i, (unsigned)(i + num)); return r.a; }
  U2 r = tf(key, (unsigned)(i - num), (unsigned)i); return r.b;
}
__device__ __forceinline__ U2 split_key(U2 key, int num, int j) {
  U2 k; k.a = split_elem(key, num, 2 * j); k.b = split_elem(key, num, 2 * j + 1);
  return k;
}
__device__ __forceinline__ unsigned random_bits(U2 key, int n, unsigned e) {
  int h = n >> 1;
  if ((int)e < h) { U2 r = tf(key, e, e + (unsigned)h); return r.a; }
  U2 r = tf(key, e - (unsigned)h, e); return r.b;
}
#endif

__device__ __forceinline__ U2 root_key() { U2 k; k.a = 0u; k.b = 42u; return k; }

__device__ __forceinline__ float jax_uniform(U2 key, int n, unsigned e,
                                             float minv, float maxv) {
  unsigned b = random_bits(key, n, e);
  float u = __uint_as_float((b >> 9) | 0x3f800000u) - 1.0f;
  float r = u * (maxv - minv) + minv;
  return fmaxf(minv, r);
}

#define ROTR 0.7853981633974483f

// Rodrigues, matching the reference op-for-op.
__device__ __forceinline__ void compute_R(float vx, float vy, float vz,
                                          float R[3][3]) {
  float nsq = vx * vx + vy * vy + vz * vz;
  float theta = sqrtf(nsq);
  if (theta < 1e-8f) {
    R[0][0] = 1.f; R[0][1] = 0.f; R[0][2] = 0.f;
    R[1][0] = 0.f; R[1][1] = 1.f; R[1][2] = 0.f;
    R[2][0] = 0.f; R[2][1] = 0.f; R[2][2] = 1.f;
    return;
  }
  float m = fmaxf(theta, 1e-8f);
  float kx = vx / m, ky = vy / m, kz = vz / m;
  float s = sinf(theta), c = cosf(theta);
  float K[3][3] = {{0.f, -kz, ky}, {kz, 0.f, -kx}, {-ky, kx, 0.f}};
  float K2[3][3];
#pragma unroll
  for (int i = 0; i < 3; i++)
#pragma unroll
    for (int j = 0; j < 3; j++)
      K2[i][j] = fmaf(K[i][2], K[2][j], fmaf(K[i][1], K[1][j], K[i][0] * K[0][j]));
  float omc = 1.0f - c;
#pragma unroll
  for (int i = 0; i < 3; i++)
#pragma unroll
    for (int j = 0; j < 3; j++)
      R[i][j] = ((i == j) ? 1.0f : 0.0f) + s * K[i][j] + omc * K2[i][j];
}

// ============================================================================
// K1: composite sort keys for the two 16384-permutations (2 rounds each).
// stream 0: src round1, 1: src round2, 2: tgt round1, 3: tgt round2
// composite = (bits << 32) | index  (stable sort == sort of composite)
// ============================================================================
__global__ __launch_bounds__(256) void bits_kernel(unsigned long long* __restrict__ bits64) {
  int gid = blockIdx.x * 256 + threadIdx.x;  // 65536
  int s = gid >> 14, i = gid & 16383;
  U2 root = root_key();
  U2 kp = split_key(root, 5, s >> 1);  // k0 for src, k1 for tgt
  U2 key;
  if ((s & 1) == 0) {
    key = split_key(kp, 2, 1);         // round1 subkey
  } else {
    U2 kA = split_key(kp, 2, 0);       // carried key after round1
    key = split_key(kA, 2, 1);         // round2 subkey
  }
  unsigned rb = random_bits(key, 16384, (unsigned)i);
  bits64[gid] = ((unsigned long long)rb << 32) | (unsigned)i;
}

// ============================================================================
// K2: O(n^2) rank counting (== stable argsort). 4 streams x 64 chunks.
// round1 -> scatter inverse (x1buf[rank] = i), round2 -> store rank.
// ============================================================================
__global__ __launch_bounds__(256) void count_kernel(
    const unsigned long long* __restrict__ bits64,
    unsigned* __restrict__ x1buf, unsigned* __restrict__ rank2) {
  int s = blockIdx.x >> 6;
  int i = ((blockIdx.x & 63) << 8) + threadIdx.x;
  const unsigned long long* sb = bits64 + ((size_t)s << 14);
  unsigned long long ci = sb[i];
  __shared__ unsigned long long tile[256];
  int cnt = 0;
  for (int t0 = 0; t0 < 16384; t0 += 256) {
    __syncthreads();
    tile[threadIdx.x] = sb[t0 + threadIdx.x];
    __syncthreads();
#pragma unroll 8
    for (int jj = 0; jj < 256; jj++) cnt += (tile[jj] < ci) ? 1 : 0;
  }
  int perm = s >> 1;
  if ((s & 1) == 0) x1buf[(perm << 14) + cnt] = (unsigned)(ci & 0xffffffffull);
  else rank2[(perm << 14) + i] = (unsigned)cnt;
}

// K3: idx[perm][rank2[i]] = x1[i] for rank2[i] < 128
__global__ __launch_bounds__(256) void idx_kernel(
    const unsigned* __restrict__ x1buf, const unsigned* __restrict__ rank2,
    int* __restrict__ idx) {
  int gid = blockIdx.x * 256 + threadIdx.x;  // 32768
  int perm = gid >> 14, i = gid & 16383;
  unsigned r = rank2[(perm << 14) + i];
  if (r < 128u) idx[perm * 128 + (int)r] = (int)x1buf[(perm << 14) + i];
}

// ============================================================================
// K4: gather src/tgt subsets, precompute yn, init population (uniform k2/k3).
// 32 blocks x 128 threads.
// ============================================================================
__global__ __launch_bounds__(128) void setup_kernel(
    const float* __restrict__ source, const float* __restrict__ target,
    const int* __restrict__ idx, float* __restrict__ src,
    float* __restrict__ tgt, float* __restrict__ yn, float* __restrict__ pop) {
  int b = blockIdx.x, tid = threadIdx.x;
  int is = idx[tid], it = idx[128 + tid];
  float y0, y1, y2;
#pragma unroll
  for (int d = 0; d < 3; d++)
    src[(b * 128 + tid) * 3 + d] = source[((size_t)b * 16384 + is) * 3 + d];
  y0 = target[((size_t)b * 16384 + it) * 3 + 0];
  y1 = target[((size_t)b * 16384 + it) * 3 + 1];
  y2 = target[((size_t)b * 16384 + it) * 3 + 2];
  tgt[(b * 128 + tid) * 3 + 0] = y0;
  tgt[(b * 128 + tid) * 3 + 1] = y1;
  tgt[(b * 128 + tid) * 3 + 2] = y2;
  yn[b * 128 + tid] = y0 * y0 + y1 * y1 + y2 * y2;

  U2 root = root_key();
  U2 k2 = split_key(root, 5, 2);
  U2 k3 = split_key(root, 5, 3);
  for (int e = tid; e < 300; e += 128) {
    int p = e / 6, d = e % 6;
    float val;
    if (p == 0) {
      val = 0.0f;
    } else {
      unsigned ridx = (unsigned)((b * 50 + p) * 3 + (d % 3));
      if (d < 3) val = jax_uniform(k2, 4800, ridx, -ROTR, ROTR);
      else       val = jax_uniform(k3, 4800, ridx, -1.0f, 1.0f);
    }
    pop[(b * 50 + p) * 6 + d] = val;
  }
}

// ============================================================================
// K5/K7: chamfer fitness of one (b,p) per 128-thread block.
// fit = mean_n min_m d2 + mean_m min_n d2,   d2 = max(xn+yn-2*cross, 0)
// ============================================================================
__global__ __launch_bounds__(128) void eval_kernel(
    const float* __restrict__ srcb, const float* __restrict__ tgtb,
    const float* __restrict__ ynb, const float* __restrict__ pose,
    float* __restrict__ fout) {
  int blk = blockIdx.x;
  int b = blk / 50, p = blk % 50;
  int tid = threadIdx.x;
  __shared__ float4 syv[128];
  __shared__ float4 xsv[128];
  __shared__ float red[128];

  {
    float y0 = tgtb[(b * 128 + tid) * 3 + 0];
    float y1 = tgtb[(b * 128 + tid) * 3 + 1];
    float y2 = tgtb[(b * 128 + tid) * 3 + 2];
    syv[tid] = make_float4(y0, y1, y2, ynb[b * 128 + tid]);
  }
  const float* v = pose + (b * 50 + p) * 6;
  float Rm[3][3];
  compute_R(v[0], v[1], v[2], Rm);
  float t0 = v[3], t1 = v[4], t2 = v[5];

  float s0 = srcb[(b * 128 + tid) * 3 + 0];
  float s1 = srcb[(b * 128 + tid) * 3 + 1];
  float s2 = srcb[(b * 128 + tid) * 3 + 2];
  float x0 = fmaf(Rm[0][2], s2, fmaf(Rm[0][1], s1, Rm[0][0] * s0)) + t0;
  float x1 = fmaf(Rm[1][2], s2, fmaf(Rm[1][1], s1, Rm[1][0] * s0)) + t1;
  float x2 = fmaf(Rm[2][2], s2, fmaf(Rm[2][1], s1, Rm[2][0] * s0)) + t2;
  float xn = x0 * x0 + x1 * x1 + x2 * x2;
  xsv[tid] = make_float4(x0, x1, x2, xn);
  __syncthreads();

  float rmin = 3.402823466e38f;
#pragma unroll 4
  for (int m = 0; m < 128; m++) {
    float4 y = syv[m];
    float cr = fmaf(x2, y.z, fmaf(x1, y.y, x0 * y.x));
    float d2 = (xn + y.w) - 2.0f * cr;
    d2 = fmaxf(d2, 0.0f);
    rmin = fminf(rmin, d2);
  }
  float4 my = syv[tid];
  float cmin = 3.402823466e38f;
#pragma unroll 4
  for (int n = 0; n < 128; n++) {
    float4 xv = xsv[n];
    float cr = fmaf(xv.z, my.z, fmaf(xv.y, my.y, xv.x * my.x));
    float d2 = (xv.w + my.w) - 2.0f * cr;
    d2 = fmaxf(d2, 0.0f);
    cmin = fminf(cmin, d2);
  }

  red[tid] = rmin;
  __syncthreads();
  for (int s = 64; s > 0; s >>= 1) {
    if (tid < s) red[tid] += red[tid + s];
    __syncthreads();
  }
  float rowsum = red[0];
  __syncthreads();
  red[tid] = cmin;
  __syncthreads();
  for (int s = 64; s > 0; s >>= 1) {
    if (tid < s) red[tid] += red[tid + s];
    __syncthreads();
  }
  if (tid == 0) fout[blk] = rowsum * 0.0078125f + red[0] * 0.0078125f;
}

// ============================================================================
// K6: per-iteration trial generation. One block per batch (64 threads).
// Applies previous iteration's selection first (it > 0).
// ============================================================================
__global__ __launch_bounds__(64) void trial_kernel(
    float* __restrict__ pop, float* __restrict__ fit, float* __restrict__ trial,
    const float* __restrict__ tfit, int it) {
  int b = blockIdx.x, tid = threadIdx.x;
  __shared__ unsigned lbits[3][50];
  __shared__ int lperm[3][50];

  if (it > 0 && tid < 50) {
    int bp = b * 50 + tid;
    if (tfit[bp] < fit[bp]) {
      fit[bp] = tfit[bp];
#pragma unroll
      for (int d = 0; d < 6; d++) pop[bp * 6 + d] = trial[bp * 6 + d];
    }
  }
  __syncthreads();

  U2 root = root_key();
  U2 kloop = split_key(root, 5, 4);
  U2 kit = split_key(kloop, 30, it);
  U2 ka = split_key(kit, 3, 0);
  U2 kb = split_key(kit, 3, 1);
  U2 kc = split_key(kit, 3, 2);

  for (int r = 0; r < 3; r++) {
    U2 pk = split_key(ka, 96, r * 32 + b);
    U2 sub = split_key(pk, 2, 1);  // _shuffle: key, subkey = split(key)
    if (tid < 50) lbits[r][tid] = random_bits(sub, 50, (unsigned)tid);
  }
  __syncthreads();
  if (tid < 50) {
    for (int r = 0; r < 3; r++) {
      unsigned bi = lbits[r][tid];
      int cnt = 0;
      for (int j = 0; j < 50; j++) {
        unsigned bj = lbits[r][j];
        cnt += (bj < bi || (bj == bi && j < tid)) ? 1 : 0;
      }
      lperm[r][cnt] = tid;  // stable-sorted values: perm[rank] = i
    }
  }
  __syncthreads();
  if (tid < 50) {
    int p = tid, bp = b * 50 + p;
    int i1 = lperm[0][p], i2 = lperm[1][p], i3 = lperm[2][p];
    U2 kc1 = split_key(kc, 2, 0), kc2 = split_key(kc, 2, 1);
    unsigned hb = random_bits(kc1, 1600, (unsigned)bp);
    unsigned lb = random_bits(kc2, 1600, (unsigned)bp);
    int jr = (int)((((hb % 6u) * 4u) + (lb % 6u)) % 6u);
#pragma unroll
    for (int d = 0; d < 6; d++) {
      float x1v = pop[(b * 50 + i1) * 6 + d];
      float x2v = pop[(b * 50 + i2) * 6 + d];
      float x3v = pop[(b * 50 + i3) * 6 + d];
      float mu = x1v + 0.8f * (x2v - x3v);
      if (d < 3) mu = fminf(fmaxf(mu, -ROTR), ROTR);
      else       mu = fminf(fmaxf(mu, -1.0f), 1.0f);
      unsigned rb = random_bits(kb, 9600, (unsigned)(bp * 6 + d));
      float u = __uint_as_float((rb >> 9) | 0x3f800000u) - 1.0f;
      bool mask = (u < 0.9f) || (d == jr);
      trial[bp * 6 + d] = mask ? mu : pop[bp * 6 + d];
    }
  }
}

// ============================================================================
// K8: final selection + per-batch argmin + R_best/t_best -> out[0:384)
// ============================================================================
__global__ __launch_bounds__(64) void final_kernel(
    float* __restrict__ pop, float* __restrict__ fit,
    const float* __restrict__ trial, const float* __restrict__ tfit,
    float* __restrict__ out) {
  int b = blockIdx.x, tid = threadIdx.x;
  __shared__ float fl[50];
  if (tid < 50) {
    int bp = b * 50 + tid;
    float f = fit[bp], tfv = tfit[bp];
    if (tfv < f) {
      f = tfv;
#pragma unroll
      for (int d = 0; d < 6; d++) pop[bp * 6 + d] = trial[bp * 6 + d];
    }
    fit[bp] = f;
    fl[tid] = f;
  }
  __syncthreads();
  if (tid == 0) {
    int best = 0;
    for (int q = 1; q < 50; q++)
      if (fl[q] < fl[best]) best = q;
    const float* v = pop + (b * 50 + best) * 6;
    float R[3][3];
    compute_R(v[0], v[1], v[2], R);
#pragma unroll
    for (int i = 0; i < 3; i++)
#pragma unroll
      for (int j = 0; j < 3; j++) out[b * 9 + i * 3 + j] = R[i][j];
    out[288 + b * 3 + 0] = v[3];
    out[288 + b * 3 + 1] = v[4];
    out[288 + b * 3 + 2] = v[5];
  }
}

// K9: aligned = source @ R_best^T + t_best  -> out[384:)
__global__ __launch_bounds__(256) void aligned_kernel(
    const float* __restrict__ source, float* __restrict__ out) {
  int gid = blockIdx.x * 256 + threadIdx.x;  // 524288 = 32*16384
  int b = gid >> 14;
  const float* R = out + b * 9;
  const float* t = out + 288 + b * 3;
  float s0 = source[(size_t)gid * 3 + 0];
  float s1 = source[(size_t)gid * 3 + 1];
  float s2 = source[(size_t)gid * 3 + 2];
  float a0 = fmaf(R[2], s2, fmaf(R[1], s1, R[0] * s0)) + t[0];
  float a1 = fmaf(R[5], s2, fmaf(R[4], s1, R[3] * s0)) + t[1];
  float a2 = fmaf(R[8], s2, fmaf(R[7], s1, R[6] * s0)) + t[2];
  out[384 + (size_t)gid * 3 + 0] = a0;
  out[384 + (size_t)gid * 3 + 1] = a1;
  out[384 + (size_t)gid * 3 + 2] = a2;
}

// ============================================================================
extern "C" void kernel_launch(void* const* d_in, const int* in_sizes, int n_in,
                              void* d_out, int out_size, void* d_ws,
                              size_t ws_size, hipStream_t stream) {
  const float* source = (const float*)d_in[0];
  const float* target = (const float*)d_in[1];
  float* out = (float*)d_out;
  char* ws = (char*)d_ws;

  // workspace layout (bytes)
  unsigned long long* bits64 = (unsigned long long*)(ws + 0);        // 524288
  unsigned* rank2 = (unsigned*)(ws + 524288);                        // 131072
  unsigned* x1buf = (unsigned*)(ws + 655360);                        // 131072
  int* idx = (int*)(ws + 786432);                                    // 1024
  float* src = (float*)(ws + 787456);                                // 49152
  float* tgt = (float*)(ws + 836608);                                // 49152
  float* yn = (float*)(ws + 885760);                                 // 16384
  float* pop = (float*)(ws + 902144);                                // 38400
  float* fit = (float*)(ws + 940544);                                // 6400
  float* trial = (float*)(ws + 946944);                              // 38400
  float* tfit = (float*)(ws + 985344);                               // 6400

  bits_kernel<<<256, 256, 0, stream>>>(bits64);
  count_kernel<<<256, 256, 0, stream>>>(bits64, x1buf, rank2);
  idx_kernel<<<128, 256, 0, stream>>>(x1buf, rank2, idx);
  setup_kernel<<<32, 128, 0, stream>>>(source, target, idx, src, tgt, yn, pop);
  eval_kernel<<<1600, 128, 0, stream>>>(src, tgt, yn, pop, fit);
  for (int it = 0; it < 30; it++) {
    trial_kernel<<<32, 64, 0, stream>>>(pop, fit, trial, tfit, it);
    eval_kernel<<<1600, 128, 0, stream>>>(src, tgt, yn, trial, tfit);
  }
  final_kernel<<<32, 64, 0, stream>>>(pop, fit, trial, tfit, out);
  aligned_kernel<<<2048, 256, 0, stream>>>(source, out);
}

// Round 2
// 919.998 us; speedup vs baseline: 1.2618x; 1.2618x over previous
//
#include <hip/hip_runtime.h>
#include <stdint.h>

// ============================================================================
// JAX threefry2x32 PRNG reproduction (partitionable semantics, verified R0).
// ============================================================================
struct U2 { unsigned a, b; };

__device__ __forceinline__ unsigned rotl32(unsigned v, int r) {
  return (v << r) | (v >> (32 - r));
}

__device__ __forceinline__ U2 tf(U2 k, unsigned x0, unsigned x1) {
  unsigned ks0 = k.a, ks1 = k.b, ks2 = k.a ^ k.b ^ 0x1BD11BDAu;
  x0 += ks0; x1 += ks1;
#define TFG(RA, RB, RC, RD, KA, KB, INC)                  \
  x0 += x1; x1 = rotl32(x1, RA); x1 ^= x0;                \
  x0 += x1; x1 = rotl32(x1, RB); x1 ^= x0;                \
  x0 += x1; x1 = rotl32(x1, RC); x1 ^= x0;                \
  x0 += x1; x1 = rotl32(x1, RD); x1 ^= x0;                \
  x0 += KA; x1 += KB + INC;
  TFG(13, 15, 26, 6, ks1, ks2, 1u)
  TFG(17, 29, 16, 24, ks2, ks0, 2u)
  TFG(13, 15, 26, 6, ks0, ks1, 3u)
  TFG(17, 29, 16, 24, ks1, ks2, 4u)
  TFG(13, 15, 26, 6, ks2, ks0, 5u)
#undef TFG
  U2 r; r.a = x0; r.b = x1; return r;
}

__device__ __forceinline__ U2 split_key(U2 key, int num, int j) {
  (void)num;
  return tf(key, 0u, (unsigned)j);
}
__device__ __forceinline__ unsigned random_bits(U2 key, int n, unsigned e) {
  (void)n;
  U2 r = tf(key, 0u, e);
  return r.a ^ r.b;
}

__device__ __forceinline__ U2 root_key() { U2 k; k.a = 0u; k.b = 42u; return k; }

__device__ __forceinline__ float jax_uniform(U2 key, int n, unsigned e,
                                             float minv, float maxv) {
  unsigned b = random_bits(key, n, e);
  float u = __uint_as_float((b >> 9) | 0x3f800000u) - 1.0f;
  float r = u * (maxv - minv) + minv;
  return fmaxf(minv, r);
}

#define ROTR 0.7853981633974483f

__device__ __forceinline__ void compute_R(float vx, float vy, float vz,
                                          float R[3][3]) {
  float nsq = vx * vx + vy * vy + vz * vz;
  float theta = sqrtf(nsq);
  if (theta < 1e-8f) {
    R[0][0] = 1.f; R[0][1] = 0.f; R[0][2] = 0.f;
    R[1][0] = 0.f; R[1][1] = 1.f; R[1][2] = 0.f;
    R[2][0] = 0.f; R[2][1] = 0.f; R[2][2] = 1.f;
    return;
  }
  float m = fmaxf(theta, 1e-8f);
  float kx = vx / m, ky = vy / m, kz = vz / m;
  float s = sinf(theta), c = cosf(theta);
  float K[3][3] = {{0.f, -kz, ky}, {kz, 0.f, -kx}, {-ky, kx, 0.f}};
  float K2[3][3];
#pragma unroll
  for (int i = 0; i < 3; i++)
#pragma unroll
    for (int j = 0; j < 3; j++)
      K2[i][j] = fmaf(K[i][2], K[2][j], fmaf(K[i][1], K[1][j], K[i][0] * K[0][j]));
  float omc = 1.0f - c;
#pragma unroll
  for (int i = 0; i < 3; i++)
#pragma unroll
    for (int j = 0; j < 3; j++)
      R[i][j] = ((i == j) ? 1.0f : 0.0f) + s * K[i][j] + omc * K2[i][j];
}

// ============================================================================
// K1: sort keys for the two 16384-permutations (2 rounds each) + zero ranks.
// stream 0: src r1, 1: src r2, 2: tgt r1, 3: tgt r2
// ============================================================================
__global__ __launch_bounds__(256) void bits_kernel(
    unsigned long long* __restrict__ bits64, unsigned* __restrict__ rank_all) {
  int gid = blockIdx.x * 256 + threadIdx.x;  // 65536
  int s = gid >> 14, i = gid & 16383;
  U2 root = root_key();
  U2 kp = split_key(root, 5, s >> 1);
  U2 key;
  if ((s & 1) == 0) {
    key = split_key(kp, 2, 1);
  } else {
    U2 kA = split_key(kp, 2, 0);
    key = split_key(kA, 2, 1);
  }
  unsigned rb = random_bits(key, 16384, (unsigned)i);
  bits64[gid] = ((unsigned long long)rb << 32) | (unsigned)i;
  rank_all[gid] = 0u;
}

// ============================================================================
// K2: rank counting, j-range split 4 ways for occupancy (1024 blocks).
// blk = (s<<8) | (chunk<<2) | jq
// ============================================================================
__global__ __launch_bounds__(256) void count4_kernel(
    const unsigned long long* __restrict__ bits64,
    unsigned* __restrict__ rank_all) {
  int blk = blockIdx.x;
  int s = blk >> 8, chunk = (blk >> 2) & 63, jq = blk & 3;
  int i = (chunk << 8) + threadIdx.x;
  const unsigned long long* sb = bits64 + ((size_t)s << 14);
  unsigned long long ci = sb[i];
  __shared__ unsigned long long tile[256];
  int cnt = 0;
  int jbase = jq << 12;
  for (int t0 = 0; t0 < 4096; t0 += 256) {
    __syncthreads();
    tile[threadIdx.x] = sb[jbase + t0 + threadIdx.x];
    __syncthreads();
#pragma unroll 8
    for (int jj = 0; jj < 256; jj++) cnt += (tile[jj] < ci) ? 1 : 0;
  }
  atomicAdd(&rank_all[(s << 14) + i], (unsigned)cnt);
}

// K3: scatter round-1 inverse: x1[perm][rank1[i]] = i   (streams 0,2)
__global__ __launch_bounds__(256) void scatter_kernel(
    const unsigned* __restrict__ rank_all, unsigned* __restrict__ x1buf) {
  int gid = blockIdx.x * 256 + threadIdx.x;  // 32768
  int perm = gid >> 14, i = gid & 16383;
  unsigned r = rank_all[((perm * 2) << 14) + i];
  x1buf[(perm << 14) + (int)r] = (unsigned)i;
}

// K4: idx[perm][rank2[i]] = x1[perm][i] for rank2[i] < 128  (streams 1,3)
__global__ __launch_bounds__(256) void idx_kernel(
    const unsigned* __restrict__ rank_all, const unsigned* __restrict__ x1buf,
    int* __restrict__ idx) {
  int gid = blockIdx.x * 256 + threadIdx.x;  // 32768
  int perm = gid >> 14, i = gid & 16383;
  unsigned r = rank_all[((perm * 2 + 1) << 14) + i];
  if (r < 128u) idx[perm * 128 + (int)r] = (int)x1buf[(perm << 14) + i];
}

// ============================================================================
// K5: gather subsets, precompute yn, init population.
// ============================================================================
__global__ __launch_bounds__(128) void setup_kernel(
    const float* __restrict__ source, const float* __restrict__ target,
    const int* __restrict__ idx, float* __restrict__ src,
    float* __restrict__ tgt, float* __restrict__ yn, float* __restrict__ pop) {
  int b = blockIdx.x, tid = threadIdx.x;
  int is = idx[tid], it = idx[128 + tid];
#pragma unroll
  for (int d = 0; d < 3; d++)
    src[(b * 128 + tid) * 3 + d] = source[((size_t)b * 16384 + is) * 3 + d];
  float y0 = target[((size_t)b * 16384 + it) * 3 + 0];
  float y1 = target[((size_t)b * 16384 + it) * 3 + 1];
  float y2 = target[((size_t)b * 16384 + it) * 3 + 2];
  tgt[(b * 128 + tid) * 3 + 0] = y0;
  tgt[(b * 128 + tid) * 3 + 1] = y1;
  tgt[(b * 128 + tid) * 3 + 2] = y2;
  yn[b * 128 + tid] = y0 * y0 + y1 * y1 + y2 * y2;

  U2 root = root_key();
  U2 k2 = split_key(root, 5, 2);
  U2 k3 = split_key(root, 5, 3);
  for (int e = tid; e < 300; e += 128) {
    int p = e / 6, d = e % 6;
    float val;
    if (p == 0) {
      val = 0.0f;
    } else {
      unsigned ridx = (unsigned)((b * 50 + p) * 3 + (d % 3));
      if (d < 3) val = jax_uniform(k2, 4800, ridx, -ROTR, ROTR);
      else       val = jax_uniform(k3, 4800, ridx, -1.0f, 1.0f);
    }
    pop[(b * 50 + p) * 6 + d] = val;
  }
}

// ============================================================================
// K6: initial fitness (eval of pop0). Math identical to R0.
// ============================================================================
__global__ __launch_bounds__(128) void eval_kernel(
    const float* __restrict__ srcb, const float* __restrict__ tgtb,
    const float* __restrict__ ynb, const float* __restrict__ pose,
    float* __restrict__ fout) {
  int blk = blockIdx.x;
  int b = blk / 50, p = blk % 50;
  int tid = threadIdx.x;
  __shared__ float4 syv[128];
  __shared__ float4 xsv[128];
  __shared__ float red[128];

  {
    float y0 = tgtb[(b * 128 + tid) * 3 + 0];
    float y1 = tgtb[(b * 128 + tid) * 3 + 1];
    float y2 = tgtb[(b * 128 + tid) * 3 + 2];
    syv[tid] = make_float4(y0, y1, y2, ynb[b * 128 + tid]);
  }
  const float* v = pose + (b * 50 + p) * 6;
  float Rm[3][3];
  compute_R(v[0], v[1], v[2], Rm);
  float t0 = v[3], t1 = v[4], t2 = v[5];

  float s0 = srcb[(b * 128 + tid) * 3 + 0];
  float s1 = srcb[(b * 128 + tid) * 3 + 1];
  float s2 = srcb[(b * 128 + tid) * 3 + 2];
  float x0 = fmaf(Rm[0][2], s2, fmaf(Rm[0][1], s1, Rm[0][0] * s0)) + t0;
  float x1 = fmaf(Rm[1][2], s2, fmaf(Rm[1][1], s1, Rm[1][0] * s0)) + t1;
  float x2 = fmaf(Rm[2][2], s2, fmaf(Rm[2][1], s1, Rm[2][0] * s0)) + t2;
  float xn = x0 * x0 + x1 * x1 + x2 * x2;
  xsv[tid] = make_float4(x0, x1, x2, xn);
  __syncthreads();

  float rmin = 3.402823466e38f;
#pragma unroll 4
  for (int m = 0; m < 128; m++) {
    float4 y = syv[m];
    float cr = fmaf(x2, y.z, fmaf(x1, y.y, x0 * y.x));
    float d2 = (xn + y.w) - 2.0f * cr;
    d2 = fmaxf(d2, 0.0f);
    rmin = fminf(rmin, d2);
  }
  float4 my = syv[tid];
  float cmin = 3.402823466e38f;
#pragma unroll 4
  for (int n = 0; n < 128; n++) {
    float4 xv = xsv[n];
    float cr = fmaf(xv.z, my.z, fmaf(xv.y, my.y, xv.x * my.x));
    float d2 = (xv.w + my.w) - 2.0f * cr;
    d2 = fmaxf(d2, 0.0f);
    cmin = fminf(cmin, d2);
  }

  red[tid] = rmin;
  __syncthreads();
  for (int s = 64; s > 0; s >>= 1) {
    if (tid < s) red[tid] += red[tid + s];
    __syncthreads();
  }
  float rowsum = red[0];
  __syncthreads();
  red[tid] = cmin;
  __syncthreads();
  for (int s = 64; s > 0; s >>= 1) {
    if (tid < s) red[tid] += red[tid + s];
    __syncthreads();
  }
  if (tid == 0) fout[blk] = rowsum * 0.0078125f + red[0] * 0.0078125f;
}

// ============================================================================
// K7: fused DE step. One block per (b,p): applies prev selection on the fly,
// derives DE permutation indices for its own p, builds trial, evaluates it.
// All arithmetic byte-identical to R0's trial_kernel + eval_kernel.
// ============================================================================
__device__ __forceinline__ float eff_pop(const float* pop_prev,
                                         const float* fit_prev,
                                         const float* trial_prev,
                                         const float* tfit_prev,
                                         int bq, int d) {
  return (tfit_prev[bq] < fit_prev[bq]) ? trial_prev[bq * 6 + d]
                                        : pop_prev[bq * 6 + d];
}

__global__ __launch_bounds__(128) void step_kernel(
    const float* __restrict__ srcb, const float* __restrict__ tgtb,
    const float* __restrict__ ynb,
    const float* __restrict__ pop_prev, const float* __restrict__ fit_prev,
    const float* __restrict__ trial_prev, const float* __restrict__ tfit_prev,
    float* __restrict__ pop_cur, float* __restrict__ fit_cur,
    float* __restrict__ trial_cur, float* __restrict__ tfit_cur, int it) {
  int blk = blockIdx.x;
  int b = blk / 50, p = blk % 50;
  int tid = threadIdx.x;
  __shared__ unsigned lbits[3][50];
  __shared__ int sel[3];
  __shared__ float strial[6];
  __shared__ float4 syv[128];
  __shared__ float4 xsv[128];
  __shared__ float red[128];

  U2 root = root_key();
  U2 kloop = split_key(root, 5, 4);
  U2 kit = split_key(kloop, 30, it);
  U2 ka = split_key(kit, 3, 0);
  U2 kb = split_key(kit, 3, 1);
  U2 kc = split_key(kit, 3, 2);

  // permutation bits for the 3 DE shuffles of this batch
  for (int e = tid; e < 150; e += 128) {
    int r = e / 50, q = e % 50;
    U2 pk = split_key(ka, 96, r * 32 + b);
    U2 sub = split_key(pk, 2, 1);
    lbits[r][q] = random_bits(sub, 50, (unsigned)q);
  }
  __syncthreads();
  // find q with stable-rank == p for each shuffle r
  for (int e = tid; e < 150; e += 128) {
    int r = e / 50, q = e % 50;
    unsigned bq = lbits[r][q];
    int cnt = 0;
    for (int j = 0; j < 50; j++) {
      unsigned bj = lbits[r][j];
      cnt += (bj < bq || (bj == bq && j < q)) ? 1 : 0;
    }
    if (cnt == p) sel[r] = q;
  }
  // stage tgt while waiting
  {
    float y0 = tgtb[(b * 128 + tid) * 3 + 0];
    float y1 = tgtb[(b * 128 + tid) * 3 + 1];
    float y2 = tgtb[(b * 128 + tid) * 3 + 2];
    syv[tid] = make_float4(y0, y1, y2, ynb[b * 128 + tid]);
  }
  __syncthreads();

  if (tid < 6) {
    int d = tid, bp = blk;
    int i1 = sel[0], i2 = sel[1], i3 = sel[2];
    float x1v = eff_pop(pop_prev, fit_prev, trial_prev, tfit_prev, b * 50 + i1, d);
    float x2v = eff_pop(pop_prev, fit_prev, trial_prev, tfit_prev, b * 50 + i2, d);
    float x3v = eff_pop(pop_prev, fit_prev, trial_prev, tfit_prev, b * 50 + i3, d);
    float mu = x1v + 0.8f * (x2v - x3v);
    if (d < 3) mu = fminf(fmaxf(mu, -ROTR), ROTR);
    else       mu = fminf(fmaxf(mu, -1.0f), 1.0f);
    U2 kc1 = split_key(kc, 2, 0), kc2 = split_key(kc, 2, 1);
    unsigned hb = random_bits(kc1, 1600, (unsigned)bp);
    unsigned lb = random_bits(kc2, 1600, (unsigned)bp);
    int jr = (int)((((hb % 6u) * 4u) + (lb % 6u)) % 6u);
    unsigned rb = random_bits(kb, 9600, (unsigned)(bp * 6 + d));
    float u = __uint_as_float((rb >> 9) | 0x3f800000u) - 1.0f;
    float pv = eff_pop(pop_prev, fit_prev, trial_prev, tfit_prev, bp, d);
    float tv = ((u < 0.9f) || (d == jr)) ? mu : pv;
    strial[d] = tv;
    trial_cur[bp * 6 + d] = tv;
    pop_cur[bp * 6 + d] = pv;
  } else if (tid == 6) {
    int bp = blk;
    float f = fit_prev[bp], tfv = tfit_prev[bp];
    fit_cur[bp] = (tfv < f) ? tfv : f;
  }
  __syncthreads();

  // ---- eval of strial (identical math to eval_kernel) ----
  float Rm[3][3];
  compute_R(strial[0], strial[1], strial[2], Rm);
  float t0 = strial[3], t1 = strial[4], t2 = strial[5];

  float s0 = srcb[(b * 128 + tid) * 3 + 0];
  float s1 = srcb[(b * 128 + tid) * 3 + 1];
  float s2 = srcb[(b * 128 + tid) * 3 + 2];
  float x0 = fmaf(Rm[0][2], s2, fmaf(Rm[0][1], s1, Rm[0][0] * s0)) + t0;
  float x1 = fmaf(Rm[1][2], s2, fmaf(Rm[1][1], s1, Rm[1][0] * s0)) + t1;
  float x2 = fmaf(Rm[2][2], s2, fmaf(Rm[2][1], s1, Rm[2][0] * s0)) + t2;
  float xn = x0 * x0 + x1 * x1 + x2 * x2;
  xsv[tid] = make_float4(x0, x1, x2, xn);
  __syncthreads();

  float rmin = 3.402823466e38f;
#pragma unroll 4
  for (int m = 0; m < 128; m++) {
    float4 y = syv[m];
    float cr = fmaf(x2, y.z, fmaf(x1, y.y, x0 * y.x));
    float d2 = (xn + y.w) - 2.0f * cr;
    d2 = fmaxf(d2, 0.0f);
    rmin = fminf(rmin, d2);
  }
  float4 my = syv[tid];
  float cmin = 3.402823466e38f;
#pragma unroll 4
  for (int n = 0; n < 128; n++) {
    float4 xv = xsv[n];
    float cr = fmaf(xv.z, my.z, fmaf(xv.y, my.y, xv.x * my.x));
    float d2 = (xv.w + my.w) - 2.0f * cr;
    d2 = fmaxf(d2, 0.0f);
    cmin = fminf(cmin, d2);
  }

  red[tid] = rmin;
  __syncthreads();
  for (int s = 64; s > 0; s >>= 1) {
    if (tid < s) red[tid] += red[tid + s];
    __syncthreads();
  }
  float rowsum = red[0];
  __syncthreads();
  red[tid] = cmin;
  __syncthreads();
  for (int s = 64; s > 0; s >>= 1) {
    if (tid < s) red[tid] += red[tid + s];
    __syncthreads();
  }
  if (tid == 0) tfit_cur[blk] = rowsum * 0.0078125f + red[0] * 0.0078125f;
}

// ============================================================================
// K8: final selection + per-batch argmin + R_best/t_best -> out[0:384)
// ============================================================================
__global__ __launch_bounds__(64) void final_kernel(
    float* __restrict__ pop, float* __restrict__ fit,
    const float* __restrict__ trial, const float* __restrict__ tfit,
    float* __restrict__ out) {
  int b = blockIdx.x, tid = threadIdx.x;
  __shared__ float fl[50];
  if (tid < 50) {
    int bp = b * 50 + tid;
    float f = fit[bp], tfv = tfit[bp];
    if (tfv < f) {
      f = tfv;
#pragma unroll
      for (int d = 0; d < 6; d++) pop[bp * 6 + d] = trial[bp * 6 + d];
    }
    fit[bp] = f;
    fl[tid] = f;
  }
  __syncthreads();
  if (tid == 0) {
    int best = 0;
    for (int q = 1; q < 50; q++)
      if (fl[q] < fl[best]) best = q;
    const float* v = pop + (b * 50 + best) * 6;
    float R[3][3];
    compute_R(v[0], v[1], v[2], R);
#pragma unroll
    for (int i = 0; i < 3; i++)
#pragma unroll
      for (int j = 0; j < 3; j++) out[b * 9 + i * 3 + j] = R[i][j];
    out[288 + b * 3 + 0] = v[3];
    out[288 + b * 3 + 1] = v[4];
    out[288 + b * 3 + 2] = v[5];
  }
}

// K9: aligned = source @ R_best^T + t_best  -> out[384:)
__global__ __launch_bounds__(256) void aligned_kernel(
    const float* __restrict__ source, float* __restrict__ out) {
  int gid = blockIdx.x * 256 + threadIdx.x;  // 524288
  int b = gid >> 14;
  const float* R = out + b * 9;
  const float* t = out + 288 + b * 3;
  float s0 = source[(size_t)gid * 3 + 0];
  float s1 = source[(size_t)gid * 3 + 1];
  float s2 = source[(size_t)gid * 3 + 2];
  float a0 = fmaf(R[2], s2, fmaf(R[1], s1, R[0] * s0)) + t[0];
  float a1 = fmaf(R[5], s2, fmaf(R[4], s1, R[3] * s0)) + t[1];
  float a2 = fmaf(R[8], s2, fmaf(R[7], s1, R[6] * s0)) + t[2];
  out[384 + (size_t)gid * 3 + 0] = a0;
  out[384 + (size_t)gid * 3 + 1] = a1;
  out[384 + (size_t)gid * 3 + 2] = a2;
}

// ============================================================================
extern "C" void kernel_launch(void* const* d_in, const int* in_sizes, int n_in,
                              void* d_out, int out_size, void* d_ws,
                              size_t ws_size, hipStream_t stream) {
  const float* source = (const float*)d_in[0];
  const float* target = (const float*)d_in[1];
  float* out = (float*)d_out;
  char* ws = (char*)d_ws;

  // --- workspace layout with overlays (phase-ordered, stream-serialized) ---
  // [0, 524288): bits64 (phase 1) -> x1buf (phase 2) -> DE state (phase 3)
  unsigned long long* bits64 = (unsigned long long*)(ws + 0);
  unsigned* x1buf = (unsigned*)(ws + 0);                    // after count4
  // DE state overlays the same region after idx built (224000 B < 524288)
  float* pop0   = (float*)(ws + 0);        // 38400 B
  float* fit0   = (float*)(ws + 38400);    // 6400 B
  float* popA   = (float*)(ws + 44800);
  float* fitA   = (float*)(ws + 83200);
  float* trialA = (float*)(ws + 89600);
  float* tfitA  = (float*)(ws + 128000);
  float* popB   = (float*)(ws + 134400);
  float* fitB   = (float*)(ws + 172800);
  float* trialB = (float*)(ws + 179200);
  float* tfitB  = (float*)(ws + 217600);   // ends 224000
  // x1buf needs to survive until idx_kernel; place it in the upper half of
  // region0 instead so DE state (written by setup, after idx) can't clash:
  x1buf = (unsigned*)(ws + 262144);                         // 131072 B, dead after idx
  unsigned* rank_all = (unsigned*)(ws + 524288);            // 262144 B
  int* idx = (int*)(ws + 786432);                           // 1024 B
  float* srcb = (float*)(ws + 787456);                      // 49152 B
  float* tgtb = (float*)(ws + 836608);                      // 49152 B
  float* ynb  = (float*)(ws + 885760);                      // 16384 B  (ends 902144)

  bits_kernel<<<256, 256, 0, stream>>>(bits64, rank_all);
  count4_kernel<<<1024, 256, 0, stream>>>(bits64, rank_all);
  scatter_kernel<<<128, 256, 0, stream>>>(rank_all, x1buf);
  idx_kernel<<<128, 256, 0, stream>>>(rank_all, x1buf, idx);
  setup_kernel<<<32, 128, 0, stream>>>(source, target, idx, srcb, tgtb, ynb, pop0);
  eval_kernel<<<1600, 128, 0, stream>>>(srcb, tgtb, ynb, pop0, fit0);

  const float* pp = pop0; const float* pf = fit0;
  const float* pt = pop0; const float* ptf = fit0;  // it=0: selection is a no-op
  for (int it = 0; it < 30; it++) {
    float* cp  = (it & 1) ? popB : popA;
    float* cf  = (it & 1) ? fitB : fitA;
    float* ct  = (it & 1) ? trialB : trialA;
    float* ctf = (it & 1) ? tfitB : tfitA;
    step_kernel<<<1600, 128, 0, stream>>>(srcb, tgtb, ynb, pp, pf, pt, ptf,
                                          cp, cf, ct, ctf, it);
    pp = cp; pf = cf; pt = ct; ptf = ctf;
  }
  // after it=29 state is in B
  final_kernel<<<32, 64, 0, stream>>>(popB, fitB, trialB, tfitB, out);
  aligned_kernel<<<2048, 256, 0, stream>>>(source, out);
}

// Round 3
// 909.683 us; speedup vs baseline: 1.2761x; 1.0113x over previous
//
#include <hip/hip_runtime.h>
#include <stdint.h>

// ============================================================================
// JAX threefry2x32 PRNG reproduction (partitionable semantics, verified R0).
// ============================================================================
struct U2 { unsigned a, b; };

__device__ __forceinline__ unsigned rotl32(unsigned v, int r) {
  return (v << r) | (v >> (32 - r));
}

__device__ __forceinline__ U2 tf(U2 k, unsigned x0, unsigned x1) {
  unsigned ks0 = k.a, ks1 = k.b, ks2 = k.a ^ k.b ^ 0x1BD11BDAu;
  x0 += ks0; x1 += ks1;
#define TFG(RA, RB, RC, RD, KA, KB, INC)                  \
  x0 += x1; x1 = rotl32(x1, RA); x1 ^= x0;                \
  x0 += x1; x1 = rotl32(x1, RB); x1 ^= x0;                \
  x0 += x1; x1 = rotl32(x1, RC); x1 ^= x0;                \
  x0 += x1; x1 = rotl32(x1, RD); x1 ^= x0;                \
  x0 += KA; x1 += KB + INC;
  TFG(13, 15, 26, 6, ks1, ks2, 1u)
  TFG(17, 29, 16, 24, ks2, ks0, 2u)
  TFG(13, 15, 26, 6, ks0, ks1, 3u)
  TFG(17, 29, 16, 24, ks1, ks2, 4u)
  TFG(13, 15, 26, 6, ks2, ks0, 5u)
#undef TFG
  U2 r; r.a = x0; r.b = x1; return r;
}

__device__ __forceinline__ U2 split_key(U2 key, int num, int j) {
  (void)num;
  return tf(key, 0u, (unsigned)j);
}
__device__ __forceinline__ unsigned random_bits(U2 key, int n, unsigned e) {
  (void)n;
  U2 r = tf(key, 0u, e);
  return r.a ^ r.b;
}

__device__ __forceinline__ U2 root_key() { U2 k; k.a = 0u; k.b = 42u; return k; }

__device__ __forceinline__ float jax_uniform(U2 key, int n, unsigned e,
                                             float minv, float maxv) {
  unsigned b = random_bits(key, n, e);
  float u = __uint_as_float((b >> 9) | 0x3f800000u) - 1.0f;
  float r = u * (maxv - minv) + minv;
  return fmaxf(minv, r);
}

#define ROTR 0.7853981633974483f

__device__ __forceinline__ void compute_R(float vx, float vy, float vz,
                                          float R[3][3]) {
  float nsq = vx * vx + vy * vy + vz * vz;
  float theta = sqrtf(nsq);
  if (theta < 1e-8f) {
    R[0][0] = 1.f; R[0][1] = 0.f; R[0][2] = 0.f;
    R[1][0] = 0.f; R[1][1] = 1.f; R[1][2] = 0.f;
    R[2][0] = 0.f; R[2][1] = 0.f; R[2][2] = 1.f;
    return;
  }
  float m = fmaxf(theta, 1e-8f);
  float kx = vx / m, ky = vy / m, kz = vz / m;
  float s = sinf(theta), c = cosf(theta);
  float K[3][3] = {{0.f, -kz, ky}, {kz, 0.f, -kx}, {-ky, kx, 0.f}};
  float K2[3][3];
#pragma unroll
  for (int i = 0; i < 3; i++)
#pragma unroll
    for (int j = 0; j < 3; j++)
      K2[i][j] = fmaf(K[i][2], K[2][j], fmaf(K[i][1], K[1][j], K[i][0] * K[0][j]));
  float omc = 1.0f - c;
#pragma unroll
  for (int i = 0; i < 3; i++)
#pragma unroll
    for (int j = 0; j < 3; j++)
      R[i][j] = ((i == j) ? 1.0f : 0.0f) + s * K[i][j] + omc * K2[i][j];
}

// composite sort key for stream s (0:src r1, 1:src r2, 2:tgt r1, 3:tgt r2)
__device__ __forceinline__ unsigned long long make_composite(int s, int i) {
  U2 root = root_key();
  U2 kp = split_key(root, 5, s >> 1);
  U2 key;
  if ((s & 1) == 0) {
    key = split_key(kp, 2, 1);
  } else {
    U2 kA = split_key(kp, 2, 0);
    key = split_key(kA, 2, 1);
  }
  unsigned rb = random_bits(key, 16384, (unsigned)i);
  return ((unsigned long long)rb << 32) | (unsigned)i;
}

// ============================================================================
// Bucket-sort rank pipeline (replaces O(n^2) count4).
// bucket = top 8 bits of random word => bucket order == key order prefix.
// rank = bucket_base + #(same-bucket composites < c)  -- deterministic.
// ============================================================================
__global__ __launch_bounds__(256) void hist_kernel(unsigned* __restrict__ hist) {
  int gid = blockIdx.x * 256 + threadIdx.x;  // 65536
  int s = gid >> 14, i = gid & 16383;
  unsigned long long c = make_composite(s, i);
  unsigned bucket = (unsigned)(c >> 56);
  atomicAdd(&hist[s * 256 + bucket], 1u);
}

__global__ __launch_bounds__(256) void prefix_kernel(
    const unsigned* __restrict__ hist, unsigned* __restrict__ base,
    unsigned* __restrict__ cursor) {
  __shared__ unsigned h[4][256];
  int t = threadIdx.x;
#pragma unroll
  for (int s = 0; s < 4; s++) h[s][t] = hist[s * 256 + t];
  __syncthreads();
#pragma unroll
  for (int s = 0; s < 4; s++) {
    unsigned acc = 0;
    for (int j = 0; j < 256; j++) acc += (j < t) ? h[s][j] : 0u;
    base[s * 256 + t] = acc;
    cursor[s * 256 + t] = acc;
  }
}

__global__ __launch_bounds__(256) void scatterb_kernel(
    unsigned* __restrict__ cursor, unsigned long long* __restrict__ sorted) {
  int gid = blockIdx.x * 256 + threadIdx.x;  // 65536
  int s = gid >> 14, i = gid & 16383;
  unsigned long long c = make_composite(s, i);
  unsigned bucket = (unsigned)(c >> 56);
  unsigned pos = atomicAdd(&cursor[s * 256 + bucket], 1u);
  sorted[(s << 14) + pos] = c;
}

__global__ __launch_bounds__(256) void rank_kernel(
    const unsigned long long* __restrict__ sorted,
    const unsigned* __restrict__ base, const unsigned* __restrict__ hist,
    unsigned* __restrict__ rank_all) {
  int gid = blockIdx.x * 256 + threadIdx.x;  // 65536
  int s = gid >> 14, k = gid & 16383;
  unsigned long long c = sorted[(s << 14) + k];
  unsigned bucket = (unsigned)(c >> 56);
  unsigned b0 = base[s * 256 + bucket];
  unsigned cnt = hist[s * 256 + bucket];
  unsigned less = 0;
  for (unsigned j = 0; j < cnt; j++)
    less += (sorted[(s << 14) + b0 + j] < c) ? 1u : 0u;
  unsigned i = (unsigned)(c & 0xffffffffull);
  rank_all[(s << 14) + i] = b0 + less;
}

// x1[perm][rank1[i]] = i   (streams 0,2)
__global__ __launch_bounds__(256) void scatter_kernel(
    const unsigned* __restrict__ rank_all, unsigned* __restrict__ x1buf) {
  int gid = blockIdx.x * 256 + threadIdx.x;  // 32768
  int perm = gid >> 14, i = gid & 16383;
  unsigned r = rank_all[((perm * 2) << 14) + i];
  x1buf[(perm << 14) + (int)r] = (unsigned)i;
}

// idx[perm][rank2[i]] = x1[perm][i] for rank2[i] < 128  (streams 1,3)
__global__ __launch_bounds__(256) void idx_kernel(
    const unsigned* __restrict__ rank_all, const unsigned* __restrict__ x1buf,
    int* __restrict__ idx) {
  int gid = blockIdx.x * 256 + threadIdx.x;  // 32768
  int perm = gid >> 14, i = gid & 16383;
  unsigned r = rank_all[((perm * 2 + 1) << 14) + i];
  if (r < 128u) idx[perm * 128 + (int)r] = (int)x1buf[(perm << 14) + i];
}

// ============================================================================
// setup: gather subsets, precompute yn, init population.
// ============================================================================
__global__ __launch_bounds__(128) void setup_kernel(
    const float* __restrict__ source, const float* __restrict__ target,
    const int* __restrict__ idx, float* __restrict__ src,
    float* __restrict__ tgt, float* __restrict__ yn, float* __restrict__ pop) {
  int b = blockIdx.x, tid = threadIdx.x;
  int is = idx[tid], it = idx[128 + tid];
#pragma unroll
  for (int d = 0; d < 3; d++)
    src[(b * 128 + tid) * 3 + d] = source[((size_t)b * 16384 + is) * 3 + d];
  float y0 = target[((size_t)b * 16384 + it) * 3 + 0];
  float y1 = target[((size_t)b * 16384 + it) * 3 + 1];
  float y2 = target[((size_t)b * 16384 + it) * 3 + 2];
  tgt[(b * 128 + tid) * 3 + 0] = y0;
  tgt[(b * 128 + tid) * 3 + 1] = y1;
  tgt[(b * 128 + tid) * 3 + 2] = y2;
  yn[b * 128 + tid] = y0 * y0 + y1 * y1 + y2 * y2;

  U2 root = root_key();
  U2 k2 = split_key(root, 5, 2);
  U2 k3 = split_key(root, 5, 3);
  for (int e = tid; e < 300; e += 128) {
    int p = e / 6, d = e % 6;
    float val;
    if (p == 0) {
      val = 0.0f;
    } else {
      unsigned ridx = (unsigned)((b * 50 + p) * 3 + (d % 3));
      if (d < 3) val = jax_uniform(k2, 4800, ridx, -ROTR, ROTR);
      else       val = jax_uniform(k3, 4800, ridx, -1.0f, 1.0f);
    }
    pop[(b * 50 + p) * 6 + d] = val;
  }
}

// ============================================================================
// Register-tiled chamfer eval core (bitwise-identical d2/min/sum vs R0/R1).
// Thread (rg=tid&31, cq=tid>>5): rows 4rg..4rg+3 in regs x cols 32cq..+31.
// Each d2 computed ONCE, feeds row accums (regs) and col partials (regs).
// ============================================================================
#define EVAL_CORE_BODY(POSE0, POSE1, POSE2, POSE3, POSE4, POSE5, OUTSTMT)      \
  {                                                                            \
    float Rm[3][3];                                                            \
    compute_R(POSE0, POSE1, POSE2, Rm);                                        \
    float t0 = POSE3, t1 = POSE4, t2 = POSE5;                                  \
    float s0 = srcb[(b * 128 + tid) * 3 + 0];                                  \
    float s1 = srcb[(b * 128 + tid) * 3 + 1];                                  \
    float s2 = srcb[(b * 128 + tid) * 3 + 2];                                  \
    float x0 = fmaf(Rm[0][2], s2, fmaf(Rm[0][1], s1, Rm[0][0] * s0)) + t0;     \
    float x1 = fmaf(Rm[1][2], s2, fmaf(Rm[1][1], s1, Rm[1][0] * s0)) + t1;     \
    float x2 = fmaf(Rm[2][2], s2, fmaf(Rm[2][1], s1, Rm[2][0] * s0)) + t2;     \
    float xn = x0 * x0 + x1 * x1 + x2 * x2;                                    \
    xsv[tid] = make_float4(x0, x1, x2, xn);                                    \
    __syncthreads();                                                           \
    int rg = tid & 31, cq = tid >> 5;                                          \
    float4 xr0 = xsv[4 * rg + 0];                                              \
    float4 xr1 = xsv[4 * rg + 1];                                              \
    float4 xr2 = xsv[4 * rg + 2];                                              \
    float4 xr3 = xsv[4 * rg + 3];                                              \
    float racc0 = 3.402823466e38f, racc1 = 3.402823466e38f;                    \
    float racc2 = 3.402823466e38f, racc3 = 3.402823466e38f;                    \
    float cacc[32];                                                            \
    _Pragma("unroll")                                                          \
    for (int cj = 0; cj < 32; cj++) {                                          \
      float4 y = syv[(cq << 5) + cj];                                          \
      float cr0 = fmaf(xr0.z, y.z, fmaf(xr0.y, y.y, xr0.x * y.x));             \
      float d0 = (xr0.w + y.w) - 2.0f * cr0; d0 = fmaxf(d0, 0.0f);             \
      float cr1 = fmaf(xr1.z, y.z, fmaf(xr1.y, y.y, xr1.x * y.x));             \
      float d1 = (xr1.w + y.w) - 2.0f * cr1; d1 = fmaxf(d1, 0.0f);             \
      float cr2 = fmaf(xr2.z, y.z, fmaf(xr2.y, y.y, xr2.x * y.x));             \
      float d2_ = (xr2.w + y.w) - 2.0f * cr2; d2_ = fmaxf(d2_, 0.0f);          \
      float cr3 = fmaf(xr3.z, y.z, fmaf(xr3.y, y.y, xr3.x * y.x));             \
      float d3 = (xr3.w + y.w) - 2.0f * cr3; d3 = fmaxf(d3, 0.0f);             \
      racc0 = fminf(racc0, d0); racc1 = fminf(racc1, d1);                      \
      racc2 = fminf(racc2, d2_); racc3 = fminf(racc3, d3);                     \
      cacc[cj] = fminf(fminf(d0, d1), fminf(d2_, d3));                         \
    }                                                                          \
    rowpart[cq * 128 + 4 * rg + 0] = racc0;                                    \
    rowpart[cq * 128 + 4 * rg + 1] = racc1;                                    \
    rowpart[cq * 128 + 4 * rg + 2] = racc2;                                    \
    rowpart[cq * 128 + 4 * rg + 3] = racc3;                                    \
    _Pragma("unroll")                                                          \
    for (int cj = 0; cj < 32; cj++)                                            \
      colpart[rg * 129 + (cq << 5) + cj] = cacc[cj];                           \
    __syncthreads();                                                           \
    float rv = rowpart[tid];                                                   \
    rv = fminf(rv, rowpart[128 + tid]);                                        \
    rv = fminf(rv, rowpart[256 + tid]);                                        \
    rv = fminf(rv, rowpart[384 + tid]);                                        \
    red[tid] = rv;                                                             \
    __syncthreads();                                                           \
    for (int s = 64; s > 0; s >>= 1) {                                         \
      if (tid < s) red[tid] += red[tid + s];                                   \
      __syncthreads();                                                         \
    }                                                                          \
    float rowsum = red[0];                                                     \
    __syncthreads();                                                           \
    float cv = colpart[tid];                                                   \
    _Pragma("unroll 4")                                                        \
    for (int rg2 = 1; rg2 < 32; rg2++)                                         \
      cv = fminf(cv, colpart[rg2 * 129 + tid]);                                \
    red[tid] = cv;                                                             \
    __syncthreads();                                                           \
    for (int s = 64; s > 0; s >>= 1) {                                         \
      if (tid < s) red[tid] += red[tid + s];                                   \
      __syncthreads();                                                         \
    }                                                                          \
    if (tid == 0) OUTSTMT;                                                     \
  }

__global__ __launch_bounds__(128) void eval_kernel(
    const float* __restrict__ srcb, const float* __restrict__ tgtb,
    const float* __restrict__ ynb, const float* __restrict__ pose,
    float* __restrict__ fout) {
  int blk = blockIdx.x;
  int b = blk / 50, p = blk % 50;
  int tid = threadIdx.x;
  __shared__ float4 syv[128];
  __shared__ float4 xsv[128];
  __shared__ float colpart[32 * 129];
  __shared__ float rowpart[4 * 128];
  __shared__ float red[128];
  {
    float y0 = tgtb[(b * 128 + tid) * 3 + 0];
    float y1 = tgtb[(b * 128 + tid) * 3 + 1];
    float y2 = tgtb[(b * 128 + tid) * 3 + 2];
    syv[tid] = make_float4(y0, y1, y2, ynb[b * 128 + tid]);
  }
  const float* v = pose + (b * 50 + p) * 6;
  EVAL_CORE_BODY(v[0], v[1], v[2], v[3], v[4], v[5],
                 fout[blk] = rowsum * 0.0078125f + red[0] * 0.0078125f)
}

// ============================================================================
// fused DE step: derive selection + DE indices + trial, then eval trial.
// ============================================================================
__device__ __forceinline__ float eff_pop(const float* pop_prev,
                                         const float* fit_prev,
                                         const float* trial_prev,
                                         const float* tfit_prev,
                                         int bq, int d) {
  return (tfit_prev[bq] < fit_prev[bq]) ? trial_prev[bq * 6 + d]
                                        : pop_prev[bq * 6 + d];
}

__global__ __launch_bounds__(128) void step_kernel(
    const float* __restrict__ srcb, const float* __restrict__ tgtb,
    const float* __restrict__ ynb,
    const float* __restrict__ pop_prev, const float* __restrict__ fit_prev,
    const float* __restrict__ trial_prev, const float* __restrict__ tfit_prev,
    float* __restrict__ pop_cur, float* __restrict__ fit_cur,
    float* __restrict__ trial_cur, float* __restrict__ tfit_cur, int it) {
  int blk = blockIdx.x;
  int b = blk / 50, p = blk % 50;
  int tid = threadIdx.x;
  __shared__ unsigned lbits[3][50];
  __shared__ int sel[3];
  __shared__ float strial[6];
  __shared__ float4 syv[128];
  __shared__ float4 xsv[128];
  __shared__ float colpart[32 * 129];
  __shared__ float rowpart[4 * 128];
  __shared__ float red[128];

  U2 root = root_key();
  U2 kloop = split_key(root, 5, 4);
  U2 kit = split_key(kloop, 30, it);
  U2 ka = split_key(kit, 3, 0);
  U2 kb = split_key(kit, 3, 1);
  U2 kc = split_key(kit, 3, 2);

  for (int e = tid; e < 150; e += 128) {
    int r = e / 50, q = e % 50;
    U2 pk = split_key(ka, 96, r * 32 + b);
    U2 sub = split_key(pk, 2, 1);
    lbits[r][q] = random_bits(sub, 50, (unsigned)q);
  }
  {
    float y0 = tgtb[(b * 128 + tid) * 3 + 0];
    float y1 = tgtb[(b * 128 + tid) * 3 + 1];
    float y2 = tgtb[(b * 128 + tid) * 3 + 2];
    syv[tid] = make_float4(y0, y1, y2, ynb[b * 128 + tid]);
  }
  __syncthreads();
  for (int e = tid; e < 150; e += 128) {
    int r = e / 50, q = e % 50;
    unsigned bq = lbits[r][q];
    int cnt = 0;
    for (int j = 0; j < 50; j++) {
      unsigned bj = lbits[r][j];
      cnt += (bj < bq || (bj == bq && j < q)) ? 1 : 0;
    }
    if (cnt == p) sel[r] = q;
  }
  __syncthreads();

  if (tid < 6) {
    int d = tid, bp = blk;
    int i1 = sel[0], i2 = sel[1], i3 = sel[2];
    float x1v = eff_pop(pop_prev, fit_prev, trial_prev, tfit_prev, b * 50 + i1, d);
    float x2v = eff_pop(pop_prev, fit_prev, trial_prev, tfit_prev, b * 50 + i2, d);
    float x3v = eff_pop(pop_prev, fit_prev, trial_prev, tfit_prev, b * 50 + i3, d);
    float mu = x1v + 0.8f * (x2v - x3v);
    if (d < 3) mu = fminf(fmaxf(mu, -ROTR), ROTR);
    else       mu = fminf(fmaxf(mu, -1.0f), 1.0f);
    U2 kc1 = split_key(kc, 2, 0), kc2 = split_key(kc, 2, 1);
    unsigned hb = random_bits(kc1, 1600, (unsigned)bp);
    unsigned lb = random_bits(kc2, 1600, (unsigned)bp);
    int jr = (int)((((hb % 6u) * 4u) + (lb % 6u)) % 6u);
    unsigned rb = random_bits(kb, 9600, (unsigned)(bp * 6 + d));
    float u = __uint_as_float((rb >> 9) | 0x3f800000u) - 1.0f;
    float pv = eff_pop(pop_prev, fit_prev, trial_prev, tfit_prev, bp, d);
    float tv = ((u < 0.9f) || (d == jr)) ? mu : pv;
    strial[d] = tv;
    trial_cur[bp * 6 + d] = tv;
    pop_cur[bp * 6 + d] = pv;
  } else if (tid == 6) {
    int bp = blk;
    float f = fit_prev[bp], tfv = tfit_prev[bp];
    fit_cur[bp] = (tfv < f) ? tfv : f;
  }
  __syncthreads();

  EVAL_CORE_BODY(strial[0], strial[1], strial[2], strial[3], strial[4],
                 strial[5],
                 tfit_cur[blk] = rowsum * 0.0078125f + red[0] * 0.0078125f)
}

// ============================================================================
// final selection + argmin + R_best/t_best -> out[0:384)
// ============================================================================
__global__ __launch_bounds__(64) void final_kernel(
    float* __restrict__ pop, float* __restrict__ fit,
    const float* __restrict__ trial, const float* __restrict__ tfit,
    float* __restrict__ out) {
  int b = blockIdx.x, tid = threadIdx.x;
  __shared__ float fl[50];
  if (tid < 50) {
    int bp = b * 50 + tid;
    float f = fit[bp], tfv = tfit[bp];
    if (tfv < f) {
      f = tfv;
#pragma unroll
      for (int d = 0; d < 6; d++) pop[bp * 6 + d] = trial[bp * 6 + d];
    }
    fit[bp] = f;
    fl[tid] = f;
  }
  __syncthreads();
  if (tid == 0) {
    int best = 0;
    for (int q = 1; q < 50; q++)
      if (fl[q] < fl[best]) best = q;
    const float* v = pop + (b * 50 + best) * 6;
    float R[3][3];
    compute_R(v[0], v[1], v[2], R);
#pragma unroll
    for (int i = 0; i < 3; i++)
#pragma unroll
      for (int j = 0; j < 3; j++) out[b * 9 + i * 3 + j] = R[i][j];
    out[288 + b * 3 + 0] = v[3];
    out[288 + b * 3 + 1] = v[4];
    out[288 + b * 3 + 2] = v[5];
  }
}

// aligned = source @ R_best^T + t_best  -> out[384:)
__global__ __launch_bounds__(256) void aligned_kernel(
    const float* __restrict__ source, float* __restrict__ out) {
  int gid = blockIdx.x * 256 + threadIdx.x;  // 524288
  int b = gid >> 14;
  const float* R = out + b * 9;
  const float* t = out + 288 + b * 3;
  float s0 = source[(size_t)gid * 3 + 0];
  float s1 = source[(size_t)gid * 3 + 1];
  float s2 = source[(size_t)gid * 3 + 2];
  float a0 = fmaf(R[2], s2, fmaf(R[1], s1, R[0] * s0)) + t[0];
  float a1 = fmaf(R[5], s2, fmaf(R[4], s1, R[3] * s0)) + t[1];
  float a2 = fmaf(R[8], s2, fmaf(R[7], s1, R[6] * s0)) + t[2];
  out[384 + (size_t)gid * 3 + 0] = a0;
  out[384 + (size_t)gid * 3 + 1] = a1;
  out[384 + (size_t)gid * 3 + 2] = a2;
}

// ============================================================================
extern "C" void kernel_launch(void* const* d_in, const int* in_sizes, int n_in,
                              void* d_out, int out_size, void* d_ws,
                              size_t ws_size, hipStream_t stream) {
  const float* source = (const float*)d_in[0];
  const float* target = (const float*)d_in[1];
  float* out = (float*)d_out;
  char* ws = (char*)d_ws;

  // --- workspace (phase-overlaid; total 799744 B < R1's proven 902144) ---
  // Region A [0, 524288): sorted (phases 1-2) -> DE state + subsets + x1buf
  unsigned long long* sorted = (unsigned long long*)(ws + 0);  // 512 KB
  float* pop0   = (float*)(ws + 0);        // 38400
  float* fit0   = (float*)(ws + 38400);
  float* popA   = (float*)(ws + 44800);
  float* fitA   = (float*)(ws + 83200);
  float* trialA = (float*)(ws + 89600);
  float* tfitA  = (float*)(ws + 128000);
  float* popB   = (float*)(ws + 134400);
  float* fitB   = (float*)(ws + 172800);
  float* trialB = (float*)(ws + 179200);
  float* tfitB  = (float*)(ws + 217600);   // ends 224000
  float* srcb   = (float*)(ws + 224000);   // 49152
  float* tgtb   = (float*)(ws + 273152);   // 49152
  float* ynb    = (float*)(ws + 322304);   // 16384 -> ends 338688
  unsigned* x1buf = (unsigned*)(ws + 338688);  // 128 KB (sorted dead by then)
  // Region B:
  unsigned* rank_all = (unsigned*)(ws + 524288);  // 256 KB
  int* idx = (int*)(ws + 786432);                 // 1 KB
  unsigned* hist   = (unsigned*)(ws + 787456);    // 4 KB
  unsigned* basep  = (unsigned*)(ws + 791552);    // 4 KB
  unsigned* cursor = (unsigned*)(ws + 795648);    // 4 KB -> ends 799744

  hipMemsetAsync(hist, 0, 4096, stream);
  hist_kernel<<<256, 256, 0, stream>>>(hist);
  prefix_kernel<<<1, 256, 0, stream>>>(hist, basep, cursor);
  scatterb_kernel<<<256, 256, 0, stream>>>(cursor, sorted);
  rank_kernel<<<256, 256, 0, stream>>>(sorted, basep, hist, rank_all);
  scatter_kernel<<<128, 256, 0, stream>>>(rank_all, x1buf);
  idx_kernel<<<128, 256, 0, stream>>>(rank_all, x1buf, idx);
  setup_kernel<<<32, 128, 0, stream>>>(source, target, idx, srcb, tgtb, ynb, pop0);
  eval_kernel<<<1600, 128, 0, stream>>>(srcb, tgtb, ynb, pop0, fit0);

  const float* pp = pop0; const float* pf = fit0;
  const float* pt = pop0; const float* ptf = fit0;  // it=0: selection no-op
  for (int it = 0; it < 30; it++) {
    float* cp  = (it & 1) ? popB : popA;
    float* cf  = (it & 1) ? fitB : fitA;
    float* ct  = (it & 1) ? trialB : trialA;
    float* ctf = (it & 1) ? tfitB : tfitA;
    step_kernel<<<1600, 128, 0, stream>>>(srcb, tgtb, ynb, pp, pf, pt, ptf,
                                          cp, cf, ct, ctf, it);
    pp = cp; pf = cf; pt = ct; ptf = ctf;
  }
  final_kernel<<<32, 64, 0, stream>>>(popB, fitB, trialB, tfitB, out);
  aligned_kernel<<<2048, 256, 0, stream>>>(source, out);
}